// Round 1
// baseline (914.924 us; speedup 1.0000x reference)
//
#include <hip/hip_runtime.h>
#include <cstdint>
#include <cmath>

typedef __bf16 bf16;
typedef __bf16 bf16x8 __attribute__((ext_vector_type(8)));
typedef __bf16 bf16x4 __attribute__((ext_vector_type(4)));
typedef float f32x4 __attribute__((ext_vector_type(4)));
typedef unsigned int u32x4 __attribute__((ext_vector_type(4)));

#define B_ 4
#define S_ 512
#define D_ 4096
#define H_ 32
#define HK_ 8
#define HD_ 128
#define ALEN_ 64
#define SCALE_ 0.08838834764831845f  // 1/sqrt(128)

// ---------------- convert f32 -> bf16 (vectorized) ----------------
__global__ __launch_bounds__(256) void k_convert(const float* __restrict__ in,
                                                 bf16* __restrict__ out, int n4) {
  int i = blockIdx.x * 256 + threadIdx.x;
  if (i >= n4) return;
  float4 v = *(const float4*)(in + (size_t)i * 4);
  bf16x4 o;
  o[0] = (bf16)v.x; o[1] = (bf16)v.y; o[2] = (bf16)v.z; o[3] = (bf16)v.w;
  *(bf16x4*)(out + (size_t)i * 4) = o;
}

// ---------- transpose + convert: in[R][C] f32 -> out[C][R] bf16 ----------
__global__ __launch_bounds__(256) void k_transpose(const float* __restrict__ in,
                                                   bf16* __restrict__ out,
                                                   int R, int C) {
  __shared__ bf16 tile[64 * 72];
  int c0 = blockIdx.x * 64, r0 = blockIdx.y * 64;
  int t = threadIdx.x;
#pragma unroll
  for (int i = 0; i < 4; ++i) {
    int q = t + i * 256;            // 0..1023 float4 chunks
    int row = q >> 4, cb = (q & 15) * 4;
    float4 v = *(const float4*)(in + (size_t)(r0 + row) * C + c0 + cb);
    bf16x4 o;
    o[0] = (bf16)v.x; o[1] = (bf16)v.y; o[2] = (bf16)v.z; o[3] = (bf16)v.w;
    *(bf16x4*)&tile[row * 72 + cb] = o;
  }
  __syncthreads();
#pragma unroll
  for (int i = 0; i < 2; ++i) {
    int q = t + i * 256;            // 0..511 ushort8 chunks
    int c = q >> 3, rb = (q & 7) * 8;
    bf16x8 o;
#pragma unroll
    for (int j = 0; j < 8; ++j) o[j] = tile[(rb + j) * 72 + c];
    *(bf16x8*)(out + (size_t)(c0 + c) * R + r0 + rb) = o;
  }
}

// ---------- GEMM: C[M][N] = A[M][K] * Bt[N][K]^T   (bf16 in, f32 acc) ----------
template <int OUTF32>
__global__ __launch_bounds__(256) void k_gemm_bt(const bf16* __restrict__ A,
                                                 const bf16* __restrict__ Bt,
                                                 void* __restrict__ Cv,
                                                 int M, int N, int K) {
  __shared__ bf16 As[128 * 40];   // 128 rows x 32 k, stride 40 (80B, 16B-aligned)
  __shared__ bf16 Bs[128 * 40];
  const int bn = blockIdx.x * 128, bm = blockIdx.y * 128;
  const int t = threadIdx.x, lane = t & 63, w = t >> 6;
  const int wm = (w >> 1) * 64, wn = (w & 1) * 64;
  const int g = lane >> 4, lr = lane & 15;
  f32x4 acc[4][4] = {};
  for (int k0 = 0; k0 < K; k0 += 32) {
    __syncthreads();
#pragma unroll
    for (int i = 0; i < 2; ++i) {
      int q = t + i * 256;          // 512 chunks of 8 bf16
      int row = q >> 2, cb = (q & 3) * 8;
      *(u32x4*)&As[row * 40 + cb] =
          *(const u32x4*)(A + (size_t)(bm + row) * K + k0 + cb);
      *(u32x4*)&Bs[row * 40 + cb] =
          *(const u32x4*)(Bt + (size_t)(bn + row) * K + k0 + cb);
    }
    __syncthreads();
    bf16x8 af[4], bfr[4];
#pragma unroll
    for (int i = 0; i < 4; ++i) {
      af[i]  = *(const bf16x8*)&As[(wm + i * 16 + lr) * 40 + g * 8];
      bfr[i] = *(const bf16x8*)&Bs[(wn + i * 16 + lr) * 40 + g * 8];
    }
#pragma unroll
    for (int i = 0; i < 4; ++i)
#pragma unroll
      for (int j = 0; j < 4; ++j)
        acc[i][j] = __builtin_amdgcn_mfma_f32_16x16x32_bf16(af[i], bfr[j], acc[i][j], 0, 0, 0);
  }
#pragma unroll
  for (int i = 0; i < 4; ++i)
#pragma unroll
    for (int j = 0; j < 4; ++j)
#pragma unroll
      for (int r = 0; r < 4; ++r) {
        size_t row = bm + wm + i * 16 + g * 4 + r;
        size_t col = bn + wn + j * 16 + lr;
        if (OUTF32)
          ((float*)Cv)[row * N + col] = acc[i][j][r];
        else
          ((bf16*)Cv)[row * N + col] = (bf16)acc[i][j][r];
      }
}

// ---------------- RoPE (in-place on bf16, interleaved pairs) ----------------
__global__ __launch_bounds__(256) void k_rope(bf16* __restrict__ X,
                                              const float* __restrict__ cosT,
                                              const float* __restrict__ sinT,
                                              int width, int total8) {
  int i = blockIdx.x * 256 + threadIdx.x;
  if (i >= total8) return;
  int perRow = width >> 3;
  int row = i / perRow;
  int c8 = (i - row * perRow) * 8;
  int s = row & (S_ - 1);
  int f = (c8 & (HD_ - 1)) >> 1;     // 0..63, multiple of 4
  float4 cv = *(const float4*)(cosT + s * (HD_ / 2) + f);
  float4 sv = *(const float4*)(sinT + s * (HD_ / 2) + f);
  float cc[4] = {cv.x, cv.y, cv.z, cv.w};
  float ss[4] = {sv.x, sv.y, sv.z, sv.w};
  bf16x8 v = *(bf16x8*)(X + (size_t)row * width + c8);
#pragma unroll
  for (int j = 0; j < 4; ++j) {
    float x0 = (float)v[2 * j], x1 = (float)v[2 * j + 1];
    v[2 * j]     = (bf16)(x0 * cc[j] - x1 * ss[j]);
    v[2 * j + 1] = (bf16)(x0 * ss[j] + x1 * cc[j]);
  }
  *(bf16x8*)(X + (size_t)row * width + c8) = v;
}

// ---------------- Attention ----------------
// K tile: row-major [64][136] (pad 8 -> 2-way max conflicts, 16B aligned)
// V tile: transposed [d][k] stride 72, k-block XOR-swizzled by bits of d>>3
__device__ __forceinline__ void stage_kv(const bf16* __restrict__ Kt,
                                         const bf16* __restrict__ Vg,
                                         bf16* __restrict__ Kl,
                                         bf16* __restrict__ Vl, int t) {
#pragma unroll
  for (int i = 0; i < 4; ++i) {
    int q = t + i * 256;            // 1024 chunks of 8
    int s = q >> 4, db = (q & 15) * 8;
    bf16x8 kv = *(const bf16x8*)(Kt + (size_t)s * (HK_ * HD_) + db);
    *(bf16x8*)&Kl[s * 136 + db] = kv;
    bf16x8 vv = *(const bf16x8*)(Vg + (size_t)s * (HK_ * HD_) + db);
    int xr = ((db >> 3) & 7) << 3;
#pragma unroll
    for (int j = 0; j < 8; ++j) {
      int d = db + j;
      Vl[d * 72 + (s ^ xr)] = vv[j];
    }
  }
}

__global__ __launch_bounds__(256) void k_attn(const bf16* __restrict__ XQ,
                                              const bf16* __restrict__ XK,
                                              const bf16* __restrict__ XV,
                                              const bf16* __restrict__ AK,
                                              const bf16* __restrict__ AV,
                                              const float* __restrict__ gate,
                                              bf16* __restrict__ O) {
  __shared__ bf16 Kl[64 * 136];
  __shared__ bf16 Vl[128 * 72];
  __shared__ bf16 Pl[4][16 * 72];
  const int qb = blockIdx.x, h = blockIdx.y, b = blockIdx.z;
  const int hk = h >> 2;            // N_REP = 4
  const int t = threadIdx.x, lane = t & 63, w = t >> 6;
  const int g = lane >> 4, lr = lane & 15;
  const int q0 = qb * 64;

  // Q fragments in registers: rows q0 + w*16 + lr, d = c*32 + g*8 + j
  bf16x8 qf[4];
  const bf16* qbase = XQ + (size_t)(b * S_ + q0 + w * 16 + lr) * (H_ * HD_) + h * HD_;
#pragma unroll
  for (int c = 0; c < 4; ++c) qf[c] = *(const bf16x8*)(qbase + c * 32 + g * 8);

  f32x4 acc_o[8] = {};
  float m_run[4], l_run[4];
#pragma unroll
  for (int r = 0; r < 4; ++r) { m_run[r] = -1e30f; l_run[r] = 0.f; }

  for (int kb = 0; kb <= qb; ++kb) {
    __syncthreads();
    stage_kv(XK + ((size_t)(b * S_ + kb * 64) * (HK_ * HD_) + hk * HD_),
             XV + ((size_t)(b * S_ + kb * 64) * (HK_ * HD_) + hk * HD_), Kl, Vl, t);
    __syncthreads();

    f32x4 sacc[4] = {};
#pragma unroll
    for (int fn = 0; fn < 4; ++fn)
#pragma unroll
      for (int c = 0; c < 4; ++c) {
        bf16x8 kf = *(const bf16x8*)&Kl[(fn * 16 + lr) * 136 + c * 32 + g * 8];
        sacc[fn] = __builtin_amdgcn_mfma_f32_16x16x32_bf16(qf[c], kf, sacc[fn], 0, 0, 0);
      }

    const bool diag = (kb == qb);
    float pv[4][4];
    float alpha[4];
#pragma unroll
    for (int r = 0; r < 4; ++r) {
      int qg = q0 + w * 16 + g * 4 + r;
      float mx = -1e30f;
      float svr[4];
#pragma unroll
      for (int fn = 0; fn < 4; ++fn) {
        float v = sacc[fn][r] * SCALE_;
        if (diag) {
          int kg = kb * 64 + fn * 16 + lr;
          if (kg > qg) v = -1e30f;
        }
        svr[fn] = v;
        mx = fmaxf(mx, v);
      }
      mx = fmaxf(mx, __shfl_xor(mx, 1));
      mx = fmaxf(mx, __shfl_xor(mx, 2));
      mx = fmaxf(mx, __shfl_xor(mx, 4));
      mx = fmaxf(mx, __shfl_xor(mx, 8));
      float mnew = fmaxf(m_run[r], mx);
      alpha[r] = __expf(m_run[r] - mnew);
      float sum = 0.f;
#pragma unroll
      for (int fn = 0; fn < 4; ++fn) {
        float p = __expf(svr[fn] - mnew);
        pv[fn][r] = p;
        sum += p;
      }
      sum += __shfl_xor(sum, 1);
      sum += __shfl_xor(sum, 2);
      sum += __shfl_xor(sum, 4);
      sum += __shfl_xor(sum, 8);
      l_run[r] = l_run[r] * alpha[r] + sum;
      m_run[r] = mnew;
    }
#pragma unroll
    for (int nb = 0; nb < 8; ++nb)
#pragma unroll
      for (int r = 0; r < 4; ++r) acc_o[nb][r] *= alpha[r];
    // P -> per-wave LDS (conflict-free writes) -> A-fragments
#pragma unroll
    for (int fn = 0; fn < 4; ++fn)
#pragma unroll
      for (int r = 0; r < 4; ++r)
        Pl[w][(g * 4 + r) * 72 + fn * 16 + lr] = (bf16)pv[fn][r];
    bf16x8 pf[2];
#pragma unroll
    for (int kk = 0; kk < 2; ++kk)
      pf[kk] = *(const bf16x8*)&Pl[w][lr * 72 + kk * 32 + g * 8];
#pragma unroll
    for (int nb = 0; nb < 8; ++nb) {
      int d = nb * 16 + lr;
      int xr = ((d >> 3) & 7) << 3;
#pragma unroll
      for (int kk = 0; kk < 2; ++kk) {
        int k0 = kk * 32 + g * 8;
        bf16x8 vf = *(const bf16x8*)&Vl[d * 72 + (k0 ^ xr)];
        acc_o[nb] = __builtin_amdgcn_mfma_f32_16x16x32_bf16(pf[kk], vf, acc_o[nb], 0, 0, 0);
      }
    }
  }
  // normalize main attention
#pragma unroll
  for (int nb = 0; nb < 8; ++nb)
#pragma unroll
    for (int r = 0; r < 4; ++r) acc_o[nb][r] /= l_run[r];

  // ---- adapter block: 64 keys, no mask, own softmax, scaled by tanh(gate) ----
  __syncthreads();
  stage_kv(AK + ((size_t)(b * ALEN_) * (HK_ * HD_) + hk * HD_),
           AV + ((size_t)(b * ALEN_) * (HK_ * HD_) + hk * HD_), Kl, Vl, t);
  __syncthreads();
  {
    f32x4 sacc[4] = {};
#pragma unroll
    for (int fn = 0; fn < 4; ++fn)
#pragma unroll
      for (int c = 0; c < 4; ++c) {
        bf16x8 kf = *(const bf16x8*)&Kl[(fn * 16 + lr) * 136 + c * 32 + g * 8];
        sacc[fn] = __builtin_amdgcn_mfma_f32_16x16x32_bf16(qf[c], kf, sacc[fn], 0, 0, 0);
      }
    float tg = tanhf(gate[h]);
    float pv[4][4];
#pragma unroll
    for (int r = 0; r < 4; ++r) {
      float mx = -1e30f;
      float svr[4];
#pragma unroll
      for (int fn = 0; fn < 4; ++fn) {
        float v = sacc[fn][r] * SCALE_;
        svr[fn] = v;
        mx = fmaxf(mx, v);
      }
      mx = fmaxf(mx, __shfl_xor(mx, 1));
      mx = fmaxf(mx, __shfl_xor(mx, 2));
      mx = fmaxf(mx, __shfl_xor(mx, 4));
      mx = fmaxf(mx, __shfl_xor(mx, 8));
      float sum = 0.f;
#pragma unroll
      for (int fn = 0; fn < 4; ++fn) {
        float p = __expf(svr[fn] - mx);
        svr[fn] = p;
        sum += p;
      }
      sum += __shfl_xor(sum, 1);
      sum += __shfl_xor(sum, 2);
      sum += __shfl_xor(sum, 4);
      sum += __shfl_xor(sum, 8);
      float fac = tg / sum;
#pragma unroll
      for (int fn = 0; fn < 4; ++fn) pv[fn][r] = svr[fn] * fac;
    }
#pragma unroll
    for (int fn = 0; fn < 4; ++fn)
#pragma unroll
      for (int r = 0; r < 4; ++r)
        Pl[w][(g * 4 + r) * 72 + fn * 16 + lr] = (bf16)pv[fn][r];
    bf16x8 pf[2];
#pragma unroll
    for (int kk = 0; kk < 2; ++kk)
      pf[kk] = *(const bf16x8*)&Pl[w][lr * 72 + kk * 32 + g * 8];
#pragma unroll
    for (int nb = 0; nb < 8; ++nb) {
      int d = nb * 16 + lr;
      int xr = ((d >> 3) & 7) << 3;
#pragma unroll
      for (int kk = 0; kk < 2; ++kk) {
        int k0 = kk * 32 + g * 8;
        bf16x8 vf = *(const bf16x8*)&Vl[d * 72 + (k0 ^ xr)];
        acc_o[nb] = __builtin_amdgcn_mfma_f32_16x16x32_bf16(pf[kk], vf, acc_o[nb], 0, 0, 0);
      }
    }
  }
  // write attention output (bf16) in [b*S+s][h*128+d] layout
  bf16* obase = O + (size_t)(b * S_ + q0 + w * 16) * (H_ * HD_) + h * HD_;
#pragma unroll
  for (int nb = 0; nb < 8; ++nb)
#pragma unroll
    for (int r = 0; r < 4; ++r)
      obase[(size_t)(g * 4 + r) * (H_ * HD_) + nb * 16 + lr] = (bf16)acc_o[nb][r];
}

// ---------------- launch ----------------
extern "C" void kernel_launch(void* const* d_in, const int* in_sizes, int n_in,
                              void* d_out, int out_size, void* d_ws, size_t ws_size,
                              hipStream_t stream) {
  const float* x       = (const float*)d_in[0];
  const float* adapter = (const float*)d_in[1];
  // d_in[2] = mask (causal tril, applied analytically)
  const float* fcos    = (const float*)d_in[3];
  const float* fsin    = (const float*)d_in[4];
  const float* wq      = (const float*)d_in[5];
  const float* wk      = (const float*)d_in[6];
  const float* wv      = (const float*)d_in[7];
  const float* wo      = (const float*)d_in[8];
  const float* gate    = (const float*)d_in[9];
  float* out = (float*)d_out;

  bf16* p = (bf16*)d_ws;
  bf16* xb  = p; p += (size_t)B_ * S_ * D_;          // 8388608
  bf16* ab  = p; p += (size_t)B_ * ALEN_ * D_;       // 1048576
  bf16* wqT = p; p += (size_t)D_ * H_ * HD_;         // 16777216 [N][K]
  bf16* wkT = p; p += (size_t)D_ * HK_ * HD_;        // 4194304
  bf16* wvT = p; p += (size_t)D_ * HK_ * HD_;        // 4194304
  bf16* woT = p; p += (size_t)D_ * H_ * HD_;         // 16777216
  bf16* xq  = p; p += (size_t)B_ * S_ * H_ * HD_;    // 8388608
  bf16* xk  = p; p += (size_t)B_ * S_ * HK_ * HD_;   // 2097152
  bf16* xv  = p; p += (size_t)B_ * S_ * HK_ * HD_;   // 2097152
  bf16* akb = p; p += (size_t)B_ * ALEN_ * HK_ * HD_;// 262144
  bf16* avb = p; p += (size_t)B_ * ALEN_ * HK_ * HD_;// 262144
  bf16* ao  = p; p += (size_t)B_ * S_ * H_ * HD_;    // 8388608
  // total ~139 MB of workspace

  dim3 blk(256);
  k_convert<<<(B_ * S_ * D_ / 4 + 255) / 256, blk, 0, stream>>>(x, xb, B_ * S_ * D_ / 4);
  k_convert<<<(B_ * ALEN_ * D_ / 4 + 255) / 256, blk, 0, stream>>>(adapter, ab, B_ * ALEN_ * D_ / 4);
  k_transpose<<<dim3(64, 64), blk, 0, stream>>>(wq, wqT, D_, H_ * HD_);
  k_transpose<<<dim3(16, 64), blk, 0, stream>>>(wk, wkT, D_, HK_ * HD_);
  k_transpose<<<dim3(16, 64), blk, 0, stream>>>(wv, wvT, D_, HK_ * HD_);
  k_transpose<<<dim3(64, 64), blk, 0, stream>>>(wo, woT, H_ * HD_, D_);

  k_gemm_bt<0><<<dim3(32, 16), blk, 0, stream>>>(xb, wqT, xq, 2048, 4096, 4096);
  k_gemm_bt<0><<<dim3(8, 16),  blk, 0, stream>>>(xb, wkT, xk, 2048, 1024, 4096);
  k_gemm_bt<0><<<dim3(8, 16),  blk, 0, stream>>>(xb, wvT, xv, 2048, 1024, 4096);
  k_gemm_bt<0><<<dim3(8, 2),   blk, 0, stream>>>(ab, wkT, akb, 256, 1024, 4096);
  k_gemm_bt<0><<<dim3(8, 2),   blk, 0, stream>>>(ab, wvT, avb, 256, 1024, 4096);

  k_rope<<<(2048 * 512 + 255) / 256, blk, 0, stream>>>(xq, fcos, fsin, 4096, 2048 * 512);
  k_rope<<<(2048 * 128 + 255) / 256, blk, 0, stream>>>(xk, fcos, fsin, 1024, 2048 * 128);

  k_attn<<<dim3(8, 32, 4), blk, 0, stream>>>(xq, xk, xv, akb, avb, gate, ao);

  k_gemm_bt<1><<<dim3(32, 16), blk, 0, stream>>>(ao, woT, out, 2048, 4096, 4096);
}

// Round 2
// 645.950 us; speedup vs baseline: 1.4164x; 1.4164x over previous
//
#include <hip/hip_runtime.h>
#include <cstdint>
#include <cmath>

typedef __bf16 bf16;
typedef __bf16 bf16x8 __attribute__((ext_vector_type(8)));
typedef __bf16 bf16x4 __attribute__((ext_vector_type(4)));
typedef float f32x4 __attribute__((ext_vector_type(4)));
typedef unsigned int u32x4 __attribute__((ext_vector_type(4)));

#define B_ 4
#define S_ 512
#define D_ 4096
#define H_ 32
#define HK_ 8
#define HD_ 128
#define ALEN_ 64
#define SCALE_ 0.08838834764831845f  // 1/sqrt(128)

#define NQKV 6144   // 4096 Q + 1024 K + 1024 V
#define MALL 2304   // 2048 x-rows + 256 adapter-rows

// global -> LDS direct (16B per lane), wave-uniform LDS base
#define GL2LDS(src, dst)                                                      \
  __builtin_amdgcn_global_load_lds(                                           \
      (const __attribute__((address_space(1))) unsigned int*)(src),           \
      (__attribute__((address_space(3))) unsigned int*)(dst), 16, 0, 0)

// ---------------- convert f32 -> bf16 (vectorized) ----------------
__global__ __launch_bounds__(256) void k_convert(const float* __restrict__ in,
                                                 bf16* __restrict__ out, int n4) {
  int i = blockIdx.x * 256 + threadIdx.x;
  if (i >= n4) return;
  float4 v = *(const float4*)(in + (size_t)i * 4);
  bf16x4 o;
  o[0] = (bf16)v.x; o[1] = (bf16)v.y; o[2] = (bf16)v.z; o[3] = (bf16)v.w;
  *(bf16x4*)(out + (size_t)i * 4) = o;
}

// ---------- transpose + convert: in[R][C] f32 -> out[C][R] bf16 ----------
__global__ __launch_bounds__(256) void k_transpose(const float* __restrict__ in,
                                                   bf16* __restrict__ out,
                                                   int R, int C) {
  __shared__ bf16 tile[64 * 72];
  int c0 = blockIdx.x * 64, r0 = blockIdx.y * 64;
  int t = threadIdx.x;
#pragma unroll
  for (int i = 0; i < 4; ++i) {
    int q = t + i * 256;            // 0..1023 float4 chunks
    int row = q >> 4, cb = (q & 15) * 4;
    float4 v = *(const float4*)(in + (size_t)(r0 + row) * C + c0 + cb);
    bf16x4 o;
    o[0] = (bf16)v.x; o[1] = (bf16)v.y; o[2] = (bf16)v.z; o[3] = (bf16)v.w;
    *(bf16x4*)&tile[row * 72 + cb] = o;
  }
  __syncthreads();
#pragma unroll
  for (int i = 0; i < 2; ++i) {
    int q = t + i * 256;            // 0..511 ushort8 chunks
    int c = q >> 3, rb = (q & 7) * 8;
    bf16x8 o;
#pragma unroll
    for (int j = 0; j < 8; ++j) o[j] = tile[(rb + j) * 72 + c];
    *(bf16x8*)(out + (size_t)(c0 + c) * R + r0 + rb) = o;
  }
}

// ---------- GEMM (m97 structure): C[M][N] = A[M][K] * Bt[N][K]^T ----------
// linear LDS [128][32], global_load_lds width=16, 2 barriers per K-step
template <int OUTF32>
__global__ __launch_bounds__(256) void k_gemm_bt(const bf16* __restrict__ A,
                                                 const bf16* __restrict__ Bt,
                                                 void* __restrict__ Cv,
                                                 int N, int K,
                                                 int lda, int ldb, int ldc) {
  __shared__ __align__(16) bf16 As[128 * 32];
  __shared__ __align__(16) bf16 Bs[128 * 32];
  const int bn = blockIdx.x * 128, bm = blockIdx.y * 128;
  const int t = threadIdx.x, lane = t & 63, w = t >> 6;
  const int wm = (w >> 1) * 64, wn = (w & 1) * 64;
  const int g = lane >> 4, lr = lane & 15;
  f32x4 acc[4][4] = {};
  for (int k0 = 0; k0 < K; k0 += 32) {
    __syncthreads();
#pragma unroll
    for (int i = 0; i < 2; ++i) {
      int q = t + i * 256;              // chunk of 8 bf16 (16B)
      int row = q >> 2, cb = (q & 3) * 8;
      int cbase = i * 256 + (t & 192);  // wave-uniform chunk base
      GL2LDS(A + (size_t)(bm + row) * lda + k0 + cb, &As[cbase * 8]);
      GL2LDS(Bt + (size_t)(bn + row) * ldb + k0 + cb, &Bs[cbase * 8]);
    }
    __syncthreads();
    bf16x8 af[4], bfr[4];
#pragma unroll
    for (int i = 0; i < 4; ++i) {
      af[i]  = *(const bf16x8*)&As[(wm + i * 16 + lr) * 32 + g * 8];
      bfr[i] = *(const bf16x8*)&Bs[(wn + i * 16 + lr) * 32 + g * 8];
    }
#pragma unroll
    for (int i = 0; i < 4; ++i)
#pragma unroll
      for (int j = 0; j < 4; ++j)
        acc[i][j] = __builtin_amdgcn_mfma_f32_16x16x32_bf16(af[i], bfr[j], acc[i][j], 0, 0, 0);
  }
#pragma unroll
  for (int i = 0; i < 4; ++i)
#pragma unroll
    for (int j = 0; j < 4; ++j)
#pragma unroll
      for (int r = 0; r < 4; ++r) {
        size_t row = bm + wm + i * 16 + g * 4 + r;
        size_t col = bn + wn + j * 16 + lr;
        if (OUTF32)
          ((float*)Cv)[row * ldc + col] = acc[i][j][r];
        else
          ((bf16*)Cv)[row * ldc + col] = (bf16)acc[i][j][r];
      }
}

// ---------------- RoPE (in-place on bf16, interleaved pairs) ----------------
__global__ __launch_bounds__(256) void k_rope(bf16* __restrict__ X,
                                              const float* __restrict__ cosT,
                                              const float* __restrict__ sinT,
                                              int width, int ldx, int total8) {
  int i = blockIdx.x * 256 + threadIdx.x;
  if (i >= total8) return;
  int perRow = width >> 3;
  int row = i / perRow;
  int c8 = (i - row * perRow) * 8;
  int s = row & (S_ - 1);
  int f = (c8 & (HD_ - 1)) >> 1;     // 0..63, multiple of 4
  float4 cv = *(const float4*)(cosT + s * (HD_ / 2) + f);
  float4 sv = *(const float4*)(sinT + s * (HD_ / 2) + f);
  float cc[4] = {cv.x, cv.y, cv.z, cv.w};
  float ss[4] = {sv.x, sv.y, sv.z, sv.w};
  bf16x8 v = *(bf16x8*)(X + (size_t)row * ldx + c8);
#pragma unroll
  for (int j = 0; j < 4; ++j) {
    float x0 = (float)v[2 * j], x1 = (float)v[2 * j + 1];
    v[2 * j]     = (bf16)(x0 * cc[j] - x1 * ss[j]);
    v[2 * j + 1] = (bf16)(x0 * ss[j] + x1 * cc[j]);
  }
  *(bf16x8*)(X + (size_t)row * ldx + c8) = v;
}

// ---------------- Attention ----------------
// K tile: row-major [64][136] (pad 8 -> 2-way max conflicts, 16B aligned)
// V tile: transposed [d][k] stride 72, k-block XOR-swizzled by bits of d>>3
__device__ __forceinline__ void stage_kv(const bf16* __restrict__ Kt,
                                         const bf16* __restrict__ Vg,
                                         bf16* __restrict__ Kl,
                                         bf16* __restrict__ Vl, int t, int ld) {
#pragma unroll
  for (int i = 0; i < 4; ++i) {
    int q = t + i * 256;            // 1024 chunks of 8
    int s = q >> 4, db = (q & 15) * 8;
    bf16x8 kv = *(const bf16x8*)(Kt + (size_t)s * ld + db);
    *(bf16x8*)&Kl[s * 136 + db] = kv;
    bf16x8 vv = *(const bf16x8*)(Vg + (size_t)s * ld + db);
    int xr = ((db >> 3) & 7) << 3;
#pragma unroll
    for (int j = 0; j < 8; ++j) {
      int d = db + j;
      Vl[d * 72 + (s ^ xr)] = vv[j];
    }
  }
}

__global__ __launch_bounds__(256) void k_attn(const bf16* __restrict__ XQ,
                                              const bf16* __restrict__ XK,
                                              const bf16* __restrict__ XV,
                                              const bf16* __restrict__ AK,
                                              const bf16* __restrict__ AV,
                                              const float* __restrict__ gate,
                                              bf16* __restrict__ O) {
  __shared__ bf16 Kl[64 * 136];
  __shared__ bf16 Vl[128 * 72];
  __shared__ bf16 Pl[4][16 * 72];
  const int qb = blockIdx.x, h = blockIdx.y, b = blockIdx.z;
  const int hk = h >> 2;            // N_REP = 4
  const int t = threadIdx.x, lane = t & 63, w = t >> 6;
  const int g = lane >> 4, lr = lane & 15;
  const int q0 = qb * 64;

  // Q fragments in registers: rows q0 + w*16 + lr, d = c*32 + g*8 + j
  bf16x8 qf[4];
  const bf16* qbase = XQ + (size_t)(b * S_ + q0 + w * 16 + lr) * NQKV + h * HD_;
#pragma unroll
  for (int c = 0; c < 4; ++c) qf[c] = *(const bf16x8*)(qbase + c * 32 + g * 8);

  f32x4 acc_o[8] = {};
  float m_run[4], l_run[4];
#pragma unroll
  for (int r = 0; r < 4; ++r) { m_run[r] = -1e30f; l_run[r] = 0.f; }

  for (int kb = 0; kb <= qb; ++kb) {
    __syncthreads();
    stage_kv(XK + ((size_t)(b * S_ + kb * 64) * NQKV + hk * HD_),
             XV + ((size_t)(b * S_ + kb * 64) * NQKV + hk * HD_), Kl, Vl, t, NQKV);
    __syncthreads();

    f32x4 sacc[4] = {};
#pragma unroll
    for (int fn = 0; fn < 4; ++fn)
#pragma unroll
      for (int c = 0; c < 4; ++c) {
        bf16x8 kf = *(const bf16x8*)&Kl[(fn * 16 + lr) * 136 + c * 32 + g * 8];
        sacc[fn] = __builtin_amdgcn_mfma_f32_16x16x32_bf16(qf[c], kf, sacc[fn], 0, 0, 0);
      }

    const bool diag = (kb == qb);
    float pv[4][4];
    float alpha[4];
#pragma unroll
    for (int r = 0; r < 4; ++r) {
      int qg = q0 + w * 16 + g * 4 + r;
      float mx = -1e30f;
      float svr[4];
#pragma unroll
      for (int fn = 0; fn < 4; ++fn) {
        float v = sacc[fn][r] * SCALE_;
        if (diag) {
          int kg = kb * 64 + fn * 16 + lr;
          if (kg > qg) v = -1e30f;
        }
        svr[fn] = v;
        mx = fmaxf(mx, v);
      }
      mx = fmaxf(mx, __shfl_xor(mx, 1));
      mx = fmaxf(mx, __shfl_xor(mx, 2));
      mx = fmaxf(mx, __shfl_xor(mx, 4));
      mx = fmaxf(mx, __shfl_xor(mx, 8));
      float mnew = fmaxf(m_run[r], mx);
      alpha[r] = __expf(m_run[r] - mnew);
      float sum = 0.f;
#pragma unroll
      for (int fn = 0; fn < 4; ++fn) {
        float p = __expf(svr[fn] - mnew);
        pv[fn][r] = p;
        sum += p;
      }
      sum += __shfl_xor(sum, 1);
      sum += __shfl_xor(sum, 2);
      sum += __shfl_xor(sum, 4);
      sum += __shfl_xor(sum, 8);
      l_run[r] = l_run[r] * alpha[r] + sum;
      m_run[r] = mnew;
    }
#pragma unroll
    for (int nb = 0; nb < 8; ++nb)
#pragma unroll
      for (int r = 0; r < 4; ++r) acc_o[nb][r] *= alpha[r];
    // P -> per-wave LDS (conflict-free writes) -> A-fragments
#pragma unroll
    for (int fn = 0; fn < 4; ++fn)
#pragma unroll
      for (int r = 0; r < 4; ++r)
        Pl[w][(g * 4 + r) * 72 + fn * 16 + lr] = (bf16)pv[fn][r];
    bf16x8 pf[2];
#pragma unroll
    for (int kk = 0; kk < 2; ++kk)
      pf[kk] = *(const bf16x8*)&Pl[w][lr * 72 + kk * 32 + g * 8];
#pragma unroll
    for (int nb = 0; nb < 8; ++nb) {
      int d = nb * 16 + lr;
      int xr = ((d >> 3) & 7) << 3;
#pragma unroll
      for (int kk = 0; kk < 2; ++kk) {
        int k0 = kk * 32 + g * 8;
        bf16x8 vf = *(const bf16x8*)&Vl[d * 72 + (k0 ^ xr)];
        acc_o[nb] = __builtin_amdgcn_mfma_f32_16x16x32_bf16(pf[kk], vf, acc_o[nb], 0, 0, 0);
      }
    }
  }
  // normalize main attention
#pragma unroll
  for (int nb = 0; nb < 8; ++nb)
#pragma unroll
    for (int r = 0; r < 4; ++r) acc_o[nb][r] /= l_run[r];

  // ---- adapter block: 64 keys, no mask, own softmax, scaled by tanh(gate) ----
  __syncthreads();
  stage_kv(AK + (size_t)(b * ALEN_) * NQKV,
           AV + (size_t)(b * ALEN_) * NQKV, Kl, Vl, t, NQKV);
  __syncthreads();
  {
    f32x4 sacc[4] = {};
#pragma unroll
    for (int fn = 0; fn < 4; ++fn)
#pragma unroll
      for (int c = 0; c < 4; ++c) {
        bf16x8 kf = *(const bf16x8*)&Kl[(fn * 16 + lr) * 136 + c * 32 + g * 8];
        sacc[fn] = __builtin_amdgcn_mfma_f32_16x16x32_bf16(qf[c], kf, sacc[fn], 0, 0, 0);
      }
    float tg = tanhf(gate[h]);
    float pv[4][4];
#pragma unroll
    for (int r = 0; r < 4; ++r) {
      float mx = -1e30f;
      float svr[4];
#pragma unroll
      for (int fn = 0; fn < 4; ++fn) {
        float v = sacc[fn][r] * SCALE_;
        svr[fn] = v;
        mx = fmaxf(mx, v);
      }
      mx = fmaxf(mx, __shfl_xor(mx, 1));
      mx = fmaxf(mx, __shfl_xor(mx, 2));
      mx = fmaxf(mx, __shfl_xor(mx, 4));
      mx = fmaxf(mx, __shfl_xor(mx, 8));
      float sum = 0.f;
#pragma unroll
      for (int fn = 0; fn < 4; ++fn) {
        float p = __expf(svr[fn] - mx);
        svr[fn] = p;
        sum += p;
      }
      sum += __shfl_xor(sum, 1);
      sum += __shfl_xor(sum, 2);
      sum += __shfl_xor(sum, 4);
      sum += __shfl_xor(sum, 8);
      float fac = tg / sum;
#pragma unroll
      for (int fn = 0; fn < 4; ++fn) pv[fn][r] = svr[fn] * fac;
    }
#pragma unroll
    for (int fn = 0; fn < 4; ++fn)
#pragma unroll
      for (int r = 0; r < 4; ++r)
        Pl[w][(g * 4 + r) * 72 + fn * 16 + lr] = (bf16)pv[fn][r];
    bf16x8 pf[2];
#pragma unroll
    for (int kk = 0; kk < 2; ++kk)
      pf[kk] = *(const bf16x8*)&Pl[w][lr * 72 + kk * 32 + g * 8];
#pragma unroll
    for (int nb = 0; nb < 8; ++nb) {
      int d = nb * 16 + lr;
      int xr = ((d >> 3) & 7) << 3;
#pragma unroll
      for (int kk = 0; kk < 2; ++kk) {
        int k0 = kk * 32 + g * 8;
        bf16x8 vf = *(const bf16x8*)&Vl[d * 72 + (k0 ^ xr)];
        acc_o[nb] = __builtin_amdgcn_mfma_f32_16x16x32_bf16(pf[kk], vf, acc_o[nb], 0, 0, 0);
      }
    }
  }
  // write attention output (bf16) in [b*S+s][h*128+d] layout
  bf16* obase = O + (size_t)(b * S_ + q0 + w * 16) * (H_ * HD_) + h * HD_;
#pragma unroll
  for (int nb = 0; nb < 8; ++nb)
#pragma unroll
    for (int r = 0; r < 4; ++r)
      obase[(size_t)(g * 4 + r) * (H_ * HD_) + nb * 16 + lr] = (bf16)acc_o[nb][r];
}

// ---------------- launch ----------------
extern "C" void kernel_launch(void* const* d_in, const int* in_sizes, int n_in,
                              void* d_out, int out_size, void* d_ws, size_t ws_size,
                              hipStream_t stream) {
  const float* x       = (const float*)d_in[0];
  const float* adapter = (const float*)d_in[1];
  // d_in[2] = mask (causal tril, applied analytically)
  const float* fcos    = (const float*)d_in[3];
  const float* fsin    = (const float*)d_in[4];
  const float* wq      = (const float*)d_in[5];
  const float* wk      = (const float*)d_in[6];
  const float* wv      = (const float*)d_in[7];
  const float* wo      = (const float*)d_in[8];
  const float* gate    = (const float*)d_in[9];
  float* out = (float*)d_out;

  bf16* p = (bf16*)d_ws;
  bf16* xall  = p; p += (size_t)MALL * D_;      // [2304][4096]: x rows + adapter rows
  bf16* wqkvT = p; p += (size_t)NQKV * D_;      // [6144][4096]: wq^T | wk^T | wv^T
  bf16* woT   = p; p += (size_t)D_ * H_ * HD_;  // [4096][4096]
  bf16* xqkv  = p; p += (size_t)MALL * NQKV;    // [2304][6144]
  bf16* ao    = p; p += (size_t)B_ * S_ * H_ * HD_;  // [2048][4096]

  dim3 blk(256);
  // convert x and adapter into one concatenated A matrix
  k_convert<<<(2048 * D_ / 4 + 255) / 256, blk, 0, stream>>>(x, xall, 2048 * D_ / 4);
  k_convert<<<(256 * D_ / 4 + 255) / 256, blk, 0, stream>>>(adapter, xall + (size_t)2048 * D_, 256 * D_ / 4);
  // weights: transpose+convert into concatenated [6144][4096]
  k_transpose<<<dim3(64, 64), blk, 0, stream>>>(wq, wqkvT, D_, H_ * HD_);
  k_transpose<<<dim3(16, 64), blk, 0, stream>>>(wk, wqkvT + (size_t)4096 * D_, D_, HK_ * HD_);
  k_transpose<<<dim3(16, 64), blk, 0, stream>>>(wv, wqkvT + (size_t)5120 * D_, D_, HK_ * HD_);
  k_transpose<<<dim3(64, 64), blk, 0, stream>>>(wo, woT, H_ * HD_, D_);

  // fused QKV (+adapter KV) projection: [2304][4096] x [6144][4096]^T
  k_gemm_bt<0><<<dim3(48, 18), blk, 0, stream>>>(xall, wqkvT, xqkv, NQKV, D_, D_, D_, NQKV);

  // RoPE on x-derived Q (cols 0..4095) and K (cols 4096..5119), rows 0..2047 only
  k_rope<<<(2048 * 512 + 255) / 256, blk, 0, stream>>>(xqkv, fcos, fsin, 4096, NQKV, 2048 * 512);
  k_rope<<<(2048 * 128 + 255) / 256, blk, 0, stream>>>(xqkv + 4096, fcos, fsin, 1024, NQKV, 2048 * 128);

  const bf16* XQ = xqkv;
  const bf16* XK = xqkv + 4096;
  const bf16* XV = xqkv + 5120;
  const bf16* AK = xqkv + (size_t)2048 * NQKV + 4096;
  const bf16* AV = xqkv + (size_t)2048 * NQKV + 5120;
  k_attn<<<dim3(8, 32, 4), blk, 0, stream>>>(XQ, XK, XV, AK, AV, gate, ao);

  // output projection -> f32
  k_gemm_bt<1><<<dim3(32, 16), blk, 0, stream>>>(ao, woT, out, D_, D_, D_, D_, D_);
}

// Round 4
// 489.701 us; speedup vs baseline: 1.8683x; 1.3191x over previous
//
#include <hip/hip_runtime.h>
#include <cstdint>
#include <cmath>

typedef __bf16 bf16;
typedef __bf16 bf16x8 __attribute__((ext_vector_type(8)));
typedef __bf16 bf16x4 __attribute__((ext_vector_type(4)));
typedef float f32x4 __attribute__((ext_vector_type(4)));
typedef unsigned int u32x4 __attribute__((ext_vector_type(4)));

#define B_ 4
#define S_ 512
#define D_ 4096
#define H_ 32
#define HK_ 8
#define HD_ 128
#define ALEN_ 64
#define SCALE_ 0.08838834764831845f  // 1/sqrt(128)

#define NQKV 6144   // 4096 Q + 1024 K + 1024 V
#define MALL 2304   // 2048 x-rows + 256 adapter-rows

// global -> LDS direct (16B per lane), wave-uniform LDS base
#define GL2LDS(src, dst)                                                      \
  __builtin_amdgcn_global_load_lds(                                           \
      (const __attribute__((address_space(1))) unsigned int*)(src),           \
      (__attribute__((address_space(3))) unsigned int*)(dst), 16, 0, 0)

#define PHASE_MID()                                        \
  {                                                        \
    asm volatile("" ::: "memory");                         \
    __builtin_amdgcn_s_barrier();                          \
    asm volatile("s_waitcnt lgkmcnt(0)" ::: "memory");     \
    __builtin_amdgcn_sched_barrier(0);                     \
  }
#define PHASE_END()                                        \
  {                                                        \
    asm volatile("" ::: "memory");                         \
    __builtin_amdgcn_s_barrier();                          \
    asm volatile("" ::: "memory");                         \
    __builtin_amdgcn_sched_barrier(0);                     \
  }

// ---------------- convert f32 -> bf16 (vectorized) ----------------
__global__ __launch_bounds__(256) void k_convert(const float* __restrict__ in,
                                                 bf16* __restrict__ out, int n4) {
  int i = blockIdx.x * 256 + threadIdx.x;
  if (i >= n4) return;
  float4 v = *(const float4*)(in + (size_t)i * 4);
  bf16x4 o;
  o[0] = (bf16)v.x; o[1] = (bf16)v.y; o[2] = (bf16)v.z; o[3] = (bf16)v.w;
  *(bf16x4*)(out + (size_t)i * 4) = o;
}

// ---------- transpose + convert: in[R][C] f32 -> out[C][R] bf16 ----------
__global__ __launch_bounds__(256) void k_transpose(const float* __restrict__ in,
                                                   bf16* __restrict__ out,
                                                   int R, int C) {
  __shared__ bf16 tile[64 * 72];
  int c0 = blockIdx.x * 64, r0 = blockIdx.y * 64;
  int t = threadIdx.x;
#pragma unroll
  for (int i = 0; i < 4; ++i) {
    int q = t + i * 256;            // 0..1023 float4 chunks
    int row = q >> 4, cb = (q & 15) * 4;
    float4 v = *(const float4*)(in + (size_t)(r0 + row) * C + c0 + cb);
    bf16x4 o;
    o[0] = (bf16)v.x; o[1] = (bf16)v.y; o[2] = (bf16)v.z; o[3] = (bf16)v.w;
    *(bf16x4*)&tile[row * 72 + cb] = o;
  }
  __syncthreads();
#pragma unroll
  for (int i = 0; i < 2; ++i) {
    int q = t + i * 256;            // 0..511 ushort8 chunks
    int c = q >> 3, rb = (q & 7) * 8;
    bf16x8 o;
#pragma unroll
    for (int j = 0; j < 8; ++j) o[j] = tile[(rb + j) * 72 + c];
    *(bf16x8*)(out + (size_t)(c0 + c) * R + r0 + rb) = o;
  }
}

// ---------- 8-phase 256-wide GEMM: C[M][N] = A[M][K] * Bt[N][K]^T ----------
// BN=256, BK=64, 8 waves (2M x 4N), double-buffered 4-region LDS,
// counted vmcnt (never 0 in main loop), raw s_barrier, XOR chunk swizzle.
template <int BM, int OUTF32>
__global__ __launch_bounds__(512, 2) void k_gemm8p(const bf16* __restrict__ A,
                                                   const bf16* __restrict__ Bt,
                                                   void* __restrict__ Cv,
                                                   int K, int lda, int ldb, int ldc) {
  constexpr int AH_ROWS = BM / 2;            // rows per A-half
  constexpr int AH_BYTES = AH_ROWS * 128;    // 64 k-cols * 2B
  constexpr int BH_BYTES = 128 * 128;        // 16 KiB per B-half
  constexpr int BUF_BYTES = 2 * AH_BYTES + 2 * BH_BYTES;
  constexpr int LA = BM / 128;               // gload_lds per thread per A-half
  constexpr int M_REP = BM / 32;             // row-frags per wave
  constexpr int MH = M_REP / 2;
  __shared__ __align__(16) unsigned char lds[2 * BUF_BYTES];

  const int bn = blockIdx.x * 256, bm = blockIdx.y * BM;
  const int tid = threadIdx.x, lane = tid & 63, w = tid >> 6;
  const int g = lane >> 4, lr = lane & 15;
  const int wm = (w >> 2) * AH_ROWS;         // 0 or BM/2
  const int wn = (w & 3) * 64;
  const int hA = w >> 2;                     // wave's A-half
  const int hB = (w & 3) >> 1;               // wave's B-half
  const int wnl = wn & 127;                  // row offset within B-half
  const int xr = lr & 7;
  const int NT = K >> 6;

  // stage one half-tile (kind: 0=A-h0,1=A-h1,2=B-h0,3=B-h1) of K-tile kt
  auto stage = [&](int kind, int kt) {
    const unsigned boff = (unsigned)(kt & 1) * BUF_BYTES;
    if (kind < 2) {
      const bf16* base = A + (size_t)(bm + kind * AH_ROWS) * lda + kt * 64;
      unsigned off = boff + kind * AH_BYTES;
#pragma unroll
      for (int i = 0; i < LA; ++i) {
        int s = tid + i * 512;
        int r = s >> 3, c = (s & 7) ^ (r & 7);   // inverse swizzle on SOURCE
        GL2LDS(base + (size_t)r * lda + c * 8,
               &lds[off + (unsigned)((tid - lane) + i * 512) * 16]);
      }
    } else {
      const bf16* base = Bt + (size_t)(bn + (kind - 2) * 128) * ldb + kt * 64;
      unsigned off = boff + 2 * AH_BYTES + (unsigned)(kind - 2) * BH_BYTES;
#pragma unroll
      for (int i = 0; i < 2; ++i) {
        int s = tid + i * 512;
        int r = s >> 3, c = (s & 7) ^ (r & 7);
        GL2LDS(base + (size_t)r * ldb + c * 8,
               &lds[off + (unsigned)((tid - lane) + i * 512) * 16]);
      }
    }
  };
  auto rdA = [&](int p, int mf, int kk) -> bf16x8 {
    unsigned addr = (unsigned)p * BUF_BYTES + (unsigned)hA * AH_BYTES +
                    (unsigned)(mf * 16 + lr) * 128 +
                    (unsigned)((((kk * 4 + g) ^ xr)) * 16);
    return *(const bf16x8*)&lds[addr];
  };
  auto rdB = [&](int p, int nf, int kk) -> bf16x8 {
    unsigned addr = (unsigned)p * BUF_BYTES + 2 * AH_BYTES + (unsigned)hB * BH_BYTES +
                    (unsigned)(wnl + nf * 16 + lr) * 128 +
                    (unsigned)((((kk * 4 + g) ^ xr)) * 16);
    return *(const bf16x8*)&lds[addr];
  };

  f32x4 acc[M_REP][4];
#pragma unroll
  for (int mf = 0; mf < M_REP; ++mf)
#pragma unroll
    for (int nf = 0; nf < 4; ++nf) acc[mf][nf] = (f32x4){0.f, 0.f, 0.f, 0.f};

  // prologue: tile0 fully, tile1 {B0, A0}; leave last 2 stages in flight
  stage(2, 0); stage(0, 0); stage(1, 0); stage(3, 0);
  stage(2, 1); stage(0, 1);
  if constexpr (BM == 256) asm volatile("s_waitcnt vmcnt(4)" ::: "memory");
  else                     asm volatile("s_waitcnt vmcnt(3)" ::: "memory");
  __builtin_amdgcn_sched_barrier(0);
  __builtin_amdgcn_s_barrier();

  bf16x8 af[M_REP], bfr[4][2];
  for (int it = 0; it < NT / 2; ++it) {
    const int t0 = 2 * it;
    const int tn2 = (t0 + 2) & (NT - 1);
    const int tn3 = (t0 + 3) & (NT - 1);
    // ---------- phase 1: A kk0 first-half + B kk0 ----------
#pragma unroll
    for (int mf = 0; mf < MH; ++mf) af[mf] = rdA(0, mf, 0);
#pragma unroll
    for (int nf = 0; nf < 4; ++nf) bfr[nf][0] = rdB(0, nf, 0);
    stage(1, t0 + 1);
    PHASE_MID();
    __builtin_amdgcn_s_setprio(1);
#pragma unroll
    for (int mf = 0; mf < MH; ++mf)
#pragma unroll
      for (int nf = 0; nf < 4; ++nf)
        acc[mf][nf] = __builtin_amdgcn_mfma_f32_16x16x32_bf16(af[mf], bfr[nf][0], acc[mf][nf], 0, 0, 0);
    __builtin_amdgcn_s_setprio(0);
    PHASE_END();
    // ---------- phase 2: A kk0 second-half + B kk1 ----------
#pragma unroll
    for (int mf = MH; mf < M_REP; ++mf) af[mf] = rdA(0, mf, 0);
#pragma unroll
    for (int nf = 0; nf < 4; ++nf) bfr[nf][1] = rdB(0, nf, 1);
    stage(3, t0 + 1);
    PHASE_MID();
    __builtin_amdgcn_s_setprio(1);
#pragma unroll
    for (int mf = MH; mf < M_REP; ++mf)
#pragma unroll
      for (int nf = 0; nf < 4; ++nf)
        acc[mf][nf] = __builtin_amdgcn_mfma_f32_16x16x32_bf16(af[mf], bfr[nf][0], acc[mf][nf], 0, 0, 0);
    __builtin_amdgcn_s_setprio(0);
    PHASE_END();
    // ---------- phase 3: A kk1 all ----------
#pragma unroll
    for (int mf = 0; mf < M_REP; ++mf) af[mf] = rdA(0, mf, 1);
    stage(2, tn2);
    PHASE_MID();
    __builtin_amdgcn_s_setprio(1);
#pragma unroll
    for (int mf = 0; mf < MH; ++mf)
#pragma unroll
      for (int nf = 0; nf < 4; ++nf)
        acc[mf][nf] = __builtin_amdgcn_mfma_f32_16x16x32_bf16(af[mf], bfr[nf][1], acc[mf][nf], 0, 0, 0);
    __builtin_amdgcn_s_setprio(0);
    PHASE_END();
    // ---------- phase 4 ----------
    stage(0, tn2);
    PHASE_MID();
    __builtin_amdgcn_s_setprio(1);
#pragma unroll
    for (int mf = MH; mf < M_REP; ++mf)
#pragma unroll
      for (int nf = 0; nf < 4; ++nf)
        acc[mf][nf] = __builtin_amdgcn_mfma_f32_16x16x32_bf16(af[mf], bfr[nf][1], acc[mf][nf], 0, 0, 0);
    __builtin_amdgcn_s_setprio(0);
    if constexpr (BM == 256) asm volatile("s_waitcnt vmcnt(4)" ::: "memory");
    else                     asm volatile("s_waitcnt vmcnt(3)" ::: "memory");
    __builtin_amdgcn_sched_barrier(0);
    PHASE_END();
    // ---------- phase 5: tile t0+1 (buf1), A kk0 first + B kk0 ----------
#pragma unroll
    for (int mf = 0; mf < MH; ++mf) af[mf] = rdA(1, mf, 0);
#pragma unroll
    for (int nf = 0; nf < 4; ++nf) bfr[nf][0] = rdB(1, nf, 0);
    stage(1, tn2);
    PHASE_MID();
    __builtin_amdgcn_s_setprio(1);
#pragma unroll
    for (int mf = 0; mf < MH; ++mf)
#pragma unroll
      for (int nf = 0; nf < 4; ++nf)
        acc[mf][nf] = __builtin_amdgcn_mfma_f32_16x16x32_bf16(af[mf], bfr[nf][0], acc[mf][nf], 0, 0, 0);
    __builtin_amdgcn_s_setprio(0);
    PHASE_END();
    // ---------- phase 6 ----------
#pragma unroll
    for (int mf = MH; mf < M_REP; ++mf) af[mf] = rdA(1, mf, 0);
#pragma unroll
    for (int nf = 0; nf < 4; ++nf) bfr[nf][1] = rdB(1, nf, 1);
    stage(3, tn2);
    PHASE_MID();
    __builtin_amdgcn_s_setprio(1);
#pragma unroll
    for (int mf = MH; mf < M_REP; ++mf)
#pragma unroll
      for (int nf = 0; nf < 4; ++nf)
        acc[mf][nf] = __builtin_amdgcn_mfma_f32_16x16x32_bf16(af[mf], bfr[nf][0], acc[mf][nf], 0, 0, 0);
    __builtin_amdgcn_s_setprio(0);
    PHASE_END();
    // ---------- phase 7 ----------
#pragma unroll
    for (int mf = 0; mf < M_REP; ++mf) af[mf] = rdA(1, mf, 1);
    stage(2, tn3);
    PHASE_MID();
    __builtin_amdgcn_s_setprio(1);
#pragma unroll
    for (int mf = 0; mf < MH; ++mf)
#pragma unroll
      for (int nf = 0; nf < 4; ++nf)
        acc[mf][nf] = __builtin_amdgcn_mfma_f32_16x16x32_bf16(af[mf], bfr[nf][1], acc[mf][nf], 0, 0, 0);
    __builtin_amdgcn_s_setprio(0);
    PHASE_END();
    // ---------- phase 8 ----------
    stage(0, tn3);
    PHASE_MID();
    __builtin_amdgcn_s_setprio(1);
#pragma unroll
    for (int mf = MH; mf < M_REP; ++mf)
#pragma unroll
      for (int nf = 0; nf < 4; ++nf)
        acc[mf][nf] = __builtin_amdgcn_mfma_f32_16x16x32_bf16(af[mf], bfr[nf][1], acc[mf][nf], 0, 0, 0);
    __builtin_amdgcn_s_setprio(0);
    if constexpr (BM == 256) asm volatile("s_waitcnt vmcnt(4)" ::: "memory");
    else                     asm volatile("s_waitcnt vmcnt(3)" ::: "memory");
    __builtin_amdgcn_sched_barrier(0);
    PHASE_END();
  }

  // epilogue: C write
#pragma unroll
  for (int mf = 0; mf < M_REP; ++mf)
#pragma unroll
    for (int nf = 0; nf < 4; ++nf)
#pragma unroll
      for (int r = 0; r < 4; ++r) {
        size_t row = (size_t)(bm + wm + mf * 16 + g * 4 + r);
        size_t col = (size_t)(bn + wn + nf * 16 + lr);
        if (OUTF32)
          ((float*)Cv)[row * ldc + col] = acc[mf][nf][r];
        else
          ((bf16*)Cv)[row * ldc + col] = (bf16)acc[mf][nf][r];
      }
}

// ---------------- RoPE (in-place on bf16, interleaved pairs) ----------------
__global__ __launch_bounds__(256) void k_rope(bf16* __restrict__ X,
                                              const float* __restrict__ cosT,
                                              const float* __restrict__ sinT,
                                              int width, int ldx, int total8) {
  int i = blockIdx.x * 256 + threadIdx.x;
  if (i >= total8) return;
  int perRow = width >> 3;
  int row = i / perRow;
  int c8 = (i - row * perRow) * 8;
  int s = row & (S_ - 1);
  int f = (c8 & (HD_ - 1)) >> 1;     // 0..63, multiple of 4
  float4 cv = *(const float4*)(cosT + s * (HD_ / 2) + f);
  float4 sv = *(const float4*)(sinT + s * (HD_ / 2) + f);
  float cc[4] = {cv.x, cv.y, cv.z, cv.w};
  float ss[4] = {sv.x, sv.y, sv.z, sv.w};
  bf16x8 v = *(bf16x8*)(X + (size_t)row * ldx + c8);
#pragma unroll
  for (int j = 0; j < 4; ++j) {
    float x0 = (float)v[2 * j], x1 = (float)v[2 * j + 1];
    v[2 * j]     = (bf16)(x0 * cc[j] - x1 * ss[j]);
    v[2 * j + 1] = (bf16)(x0 * ss[j] + x1 * cc[j]);
  }
  *(bf16x8*)(X + (size_t)row * ldx + c8) = v;
}

// ---------------- Attention ----------------
// K tile: row-major [64][136] (pad 8 -> 2-way max conflicts, 16B aligned)
// V tile: transposed [d][k] stride 72, k-block XOR-swizzled by bits of d>>3
__device__ __forceinline__ void stage_kv(const bf16* __restrict__ Kt,
                                         const bf16* __restrict__ Vg,
                                         bf16* __restrict__ Kl,
                                         bf16* __restrict__ Vl, int t, int ld) {
#pragma unroll
  for (int i = 0; i < 4; ++i) {
    int q = t + i * 256;            // 1024 chunks of 8
    int s = q >> 4, db = (q & 15) * 8;
    bf16x8 kv = *(const bf16x8*)(Kt + (size_t)s * ld + db);
    *(bf16x8*)&Kl[s * 136 + db] = kv;
    bf16x8 vv = *(const bf16x8*)(Vg + (size_t)s * ld + db);
    int xr = ((db >> 3) & 7) << 3;
#pragma unroll
    for (int j = 0; j < 8; ++j) {
      int d = db + j;
      Vl[d * 72 + (s ^ xr)] = vv[j];
    }
  }
}

__global__ __launch_bounds__(256) void k_attn(const bf16* __restrict__ XQ,
                                              const bf16* __restrict__ XK,
                                              const bf16* __restrict__ XV,
                                              const bf16* __restrict__ AK,
                                              const bf16* __restrict__ AV,
                                              const float* __restrict__ gate,
                                              bf16* __restrict__ O) {
  __shared__ bf16 Kl[64 * 136];
  __shared__ bf16 Vl[128 * 72];
  __shared__ bf16 Pl[4][16 * 72];
  const int qb = blockIdx.x, h = blockIdx.y, b = blockIdx.z;
  const int hk = h >> 2;            // N_REP = 4
  const int t = threadIdx.x, lane = t & 63, w = t >> 6;
  const int g = lane >> 4, lr = lane & 15;
  const int q0 = qb * 64;

  // Q fragments in registers: rows q0 + w*16 + lr, d = c*32 + g*8 + j
  bf16x8 qf[4];
  const bf16* qbase = XQ + (size_t)(b * S_ + q0 + w * 16 + lr) * NQKV + h * HD_;
#pragma unroll
  for (int c = 0; c < 4; ++c) qf[c] = *(const bf16x8*)(qbase + c * 32 + g * 8);

  f32x4 acc_o[8] = {};
  float m_run[4], l_run[4];
#pragma unroll
  for (int r = 0; r < 4; ++r) { m_run[r] = -1e30f; l_run[r] = 0.f; }

  for (int kb = 0; kb <= qb; ++kb) {
    __syncthreads();
    stage_kv(XK + ((size_t)(b * S_ + kb * 64) * NQKV + hk * HD_),
             XV + ((size_t)(b * S_ + kb * 64) * NQKV + hk * HD_), Kl, Vl, t, NQKV);
    __syncthreads();

    f32x4 sacc[4] = {};
#pragma unroll
    for (int fn = 0; fn < 4; ++fn)
#pragma unroll
      for (int c = 0; c < 4; ++c) {
        bf16x8 kf = *(const bf16x8*)&Kl[(fn * 16 + lr) * 136 + c * 32 + g * 8];
        sacc[fn] = __builtin_amdgcn_mfma_f32_16x16x32_bf16(qf[c], kf, sacc[fn], 0, 0, 0);
      }

    const bool diag = (kb == qb);
    float pv[4][4];
    float alpha[4];
#pragma unroll
    for (int r = 0; r < 4; ++r) {
      int qg = q0 + w * 16 + g * 4 + r;
      float mx = -1e30f;
      float svr[4];
#pragma unroll
      for (int fn = 0; fn < 4; ++fn) {
        float v = sacc[fn][r] * SCALE_;
        if (diag) {
          int kg = kb * 64 + fn * 16 + lr;
          if (kg > qg) v = -1e30f;
        }
        svr[fn] = v;
        mx = fmaxf(mx, v);
      }
      mx = fmaxf(mx, __shfl_xor(mx, 1));
      mx = fmaxf(mx, __shfl_xor(mx, 2));
      mx = fmaxf(mx, __shfl_xor(mx, 4));
      mx = fmaxf(mx, __shfl_xor(mx, 8));
      float mnew = fmaxf(m_run[r], mx);
      alpha[r] = __expf(m_run[r] - mnew);
      float sum = 0.f;
#pragma unroll
      for (int fn = 0; fn < 4; ++fn) {
        float p = __expf(svr[fn] - mnew);
        pv[fn][r] = p;
        sum += p;
      }
      sum += __shfl_xor(sum, 1);
      sum += __shfl_xor(sum, 2);
      sum += __shfl_xor(sum, 4);
      sum += __shfl_xor(sum, 8);
      l_run[r] = l_run[r] * alpha[r] + sum;
      m_run[r] = mnew;
    }
#pragma unroll
    for (int nb = 0; nb < 8; ++nb)
#pragma unroll
      for (int r = 0; r < 4; ++r) acc_o[nb][r] *= alpha[r];
    // P -> per-wave LDS (conflict-free writes) -> A-fragments
#pragma unroll
    for (int fn = 0; fn < 4; ++fn)
#pragma unroll
      for (int r = 0; r < 4; ++r)
        Pl[w][(g * 4 + r) * 72 + fn * 16 + lr] = (bf16)pv[fn][r];
    bf16x8 pf[2];
#pragma unroll
    for (int kk = 0; kk < 2; ++kk)
      pf[kk] = *(const bf16x8*)&Pl[w][lr * 72 + kk * 32 + g * 8];
#pragma unroll
    for (int nb = 0; nb < 8; ++nb) {
      int d = nb * 16 + lr;
      int xr = ((d >> 3) & 7) << 3;
#pragma unroll
      for (int kk = 0; kk < 2; ++kk) {
        int k0 = kk * 32 + g * 8;
        bf16x8 vf = *(const bf16x8*)&Vl[d * 72 + (k0 ^ xr)];
        acc_o[nb] = __builtin_amdgcn_mfma_f32_16x16x32_bf16(pf[kk], vf, acc_o[nb], 0, 0, 0);
      }
    }
  }
  // normalize main attention
#pragma unroll
  for (int nb = 0; nb < 8; ++nb)
#pragma unroll
    for (int r = 0; r < 4; ++r) acc_o[nb][r] /= l_run[r];

  // ---- adapter block: 64 keys, no mask, own softmax, scaled by tanh(gate) ----
  __syncthreads();
  stage_kv(AK + (size_t)(b * ALEN_) * NQKV,
           AV + (size_t)(b * ALEN_) * NQKV, Kl, Vl, t, NQKV);
  __syncthreads();
  {
    f32x4 sacc[4] = {};
#pragma unroll
    for (int fn = 0; fn < 4; ++fn)
#pragma unroll
      for (int c = 0; c < 4; ++c) {
        bf16x8 kf = *(const bf16x8*)&Kl[(fn * 16 + lr) * 136 + c * 32 + g * 8];
        sacc[fn] = __builtin_amdgcn_mfma_f32_16x16x32_bf16(qf[c], kf, sacc[fn], 0, 0, 0);
      }
    float tg = tanhf(gate[h]);
    float pv[4][4];
#pragma unroll
    for (int r = 0; r < 4; ++r) {
      float mx = -1e30f;
      float svr[4];
#pragma unroll
      for (int fn = 0; fn < 4; ++fn) {
        float v = sacc[fn][r] * SCALE_;
        svr[fn] = v;
        mx = fmaxf(mx, v);
      }
      mx = fmaxf(mx, __shfl_xor(mx, 1));
      mx = fmaxf(mx, __shfl_xor(mx, 2));
      mx = fmaxf(mx, __shfl_xor(mx, 4));
      mx = fmaxf(mx, __shfl_xor(mx, 8));
      float sum = 0.f;
#pragma unroll
      for (int fn = 0; fn < 4; ++fn) {
        float p = __expf(svr[fn] - mx);
        svr[fn] = p;
        sum += p;
      }
      sum += __shfl_xor(sum, 1);
      sum += __shfl_xor(sum, 2);
      sum += __shfl_xor(sum, 4);
      sum += __shfl_xor(sum, 8);
      float fac = tg / sum;
#pragma unroll
      for (int fn = 0; fn < 4; ++fn) pv[fn][r] = svr[fn] * fac;
    }
#pragma unroll
    for (int fn = 0; fn < 4; ++fn)
#pragma unroll
      for (int r = 0; r < 4; ++r)
        Pl[w][(g * 4 + r) * 72 + fn * 16 + lr] = (bf16)pv[fn][r];
    bf16x8 pf[2];
#pragma unroll
    for (int kk = 0; kk < 2; ++kk)
      pf[kk] = *(const bf16x8*)&Pl[w][lr * 72 + kk * 32 + g * 8];
#pragma unroll
    for (int nb = 0; nb < 8; ++nb) {
      int d = nb * 16 + lr;
      int xr = ((d >> 3) & 7) << 3;
#pragma unroll
      for (int kk = 0; kk < 2; ++kk) {
        int k0 = kk * 32 + g * 8;
        bf16x8 vf = *(const bf16x8*)&Vl[d * 72 + (k0 ^ xr)];
        acc_o[nb] = __builtin_amdgcn_mfma_f32_16x16x32_bf16(pf[kk], vf, acc_o[nb], 0, 0, 0);
      }
    }
  }
  // write attention output (bf16) in [b*S+s][h*128+d] layout
  bf16* obase = O + (size_t)(b * S_ + q0 + w * 16) * (H_ * HD_) + h * HD_;
#pragma unroll
  for (int nb = 0; nb < 8; ++nb)
#pragma unroll
    for (int r = 0; r < 4; ++r)
      obase[(size_t)(g * 4 + r) * (H_ * HD_) + nb * 16 + lr] = (bf16)acc_o[nb][r];
}

// ---------------- launch ----------------
extern "C" void kernel_launch(void* const* d_in, const int* in_sizes, int n_in,
                              void* d_out, int out_size, void* d_ws, size_t ws_size,
                              hipStream_t stream) {
  const float* x       = (const float*)d_in[0];
  const float* adapter = (const float*)d_in[1];
  // d_in[2] = mask (causal tril, applied analytically)
  const float* fcos    = (const float*)d_in[3];
  const float* fsin    = (const float*)d_in[4];
  const float* wq      = (const float*)d_in[5];
  const float* wk      = (const float*)d_in[6];
  const float* wv      = (const float*)d_in[7];
  const float* wo      = (const float*)d_in[8];
  const float* gate    = (const float*)d_in[9];
  float* out = (float*)d_out;

  bf16* p = (bf16*)d_ws;
  bf16* xall  = p; p += (size_t)MALL * D_;      // [2304][4096]: x rows + adapter rows
  bf16* wqkvT = p; p += (size_t)NQKV * D_;      // [6144][4096]: wq^T | wk^T | wv^T
  bf16* woT   = p; p += (size_t)D_ * H_ * HD_;  // [4096][4096]
  bf16* xqkv  = p; p += (size_t)MALL * NQKV;    // [2304][6144]
  bf16* ao    = p; p += (size_t)B_ * S_ * H_ * HD_;  // [2048][4096]

  dim3 blk(256);
  // convert x and adapter into one concatenated A matrix
  k_convert<<<(2048 * D_ / 4 + 255) / 256, blk, 0, stream>>>(x, xall, 2048 * D_ / 4);
  k_convert<<<(256 * D_ / 4 + 255) / 256, blk, 0, stream>>>(adapter, xall + (size_t)2048 * D_, 256 * D_ / 4);
  // weights: transpose+convert into concatenated [6144][4096]
  k_transpose<<<dim3(64, 64), blk, 0, stream>>>(wq, wqkvT, D_, H_ * HD_);
  k_transpose<<<dim3(16, 64), blk, 0, stream>>>(wk, wqkvT + (size_t)4096 * D_, D_, HK_ * HD_);
  k_transpose<<<dim3(16, 64), blk, 0, stream>>>(wv, wqkvT + (size_t)5120 * D_, D_, HK_ * HD_);
  k_transpose<<<dim3(64, 64), blk, 0, stream>>>(wo, woT, H_ * HD_, D_);

  // fused QKV (+adapter KV) projection: [2304][4096] x [6144][4096]^T
  k_gemm8p<256, 0><<<dim3(24, 9), dim3(512), 0, stream>>>(xall, wqkvT, xqkv, D_, D_, D_, NQKV);

  // RoPE on x-derived Q (cols 0..4095) and K (cols 4096..5119), rows 0..2047 only
  k_rope<<<(2048 * 512 + 255) / 256, blk, 0, stream>>>(xqkv, fcos, fsin, 4096, NQKV, 2048 * 512);
  k_rope<<<(2048 * 128 + 255) / 256, blk, 0, stream>>>(xqkv + 4096, fcos, fsin, 1024, NQKV, 2048 * 128);

  const bf16* XQ = xqkv;
  const bf16* XK = xqkv + 4096;
  const bf16* XV = xqkv + 5120;
  const bf16* AK = xqkv + (size_t)2048 * NQKV + 4096;
  const bf16* AV = xqkv + (size_t)2048 * NQKV + 5120;
  k_attn<<<dim3(8, 32, 4), blk, 0, stream>>>(XQ, XK, XV, AK, AV, gate, ao);

  // output projection -> f32 (BM=128 x BN=256 grid -> 256 blocks, full device)
  k_gemm8p<128, 1><<<dim3(16, 16), dim3(512), 0, stream>>>(ao, woT, out, D_, D_, D_, D_);
}